// Round 5
// baseline (1237.955 us; speedup 1.0000x reference)
//
#include <hip/hip_runtime.h>

// EPN_flax, round 14: round-12 numerics (both directions — round 13 proved the
// single-evaluation trick invalid: elec_ji uses e[i,j], not e[j,i], and e is
// asymmetric), with the register diet done via LDS instead of spill:
// Aw0a/Aw0b weight frags move to LDS (per-lane uint4 reads, conflict-free),
// -32 persistent VGPRs -> ~113 live, fits the (256,4) 128-reg cap with slack.
// Grid dim3(16,64) = 1024 blocks = exactly 4/CU co-resident, 16 waves/CU
// (round 12 ran 2/CU with ~10 regs spilling: WRITE 40 MB, FETCH 132 MB, 88us).
// U-pass and V-pass split into separate t-loops to cap peak temporaries.
// Everything else as round 12: barrier-free main loop after one sync, shared
// e-load for both directions, q_j hi/lo in spare e-term k-slots, pk-relu,
// sigma-permuted W1 layer 2, w2s=16*W2 epilogue, per-i register accumulation.

constexpr int Nn = 1024;

typedef _Float16 half8 __attribute__((ext_vector_type(8)));
typedef __fp16   fp16x2 __attribute__((ext_vector_type(2)));
typedef float    f32x4 __attribute__((ext_vector_type(4)));
typedef unsigned int uint4v __attribute__((ext_vector_type(4)));

#define MFMAH32(A, B, C) __builtin_amdgcn_mfma_f32_16x16x32_f16(A, B, C, 0, 0, 0)

__device__ inline unsigned int pkrtz(float a, float b) {
    fp16x2 r = __builtin_amdgcn_cvt_pkrtz(a, b);
    return __builtin_bit_cast(unsigned int, r);
}
__device__ inline f32x4 max0(f32x4 a) {
    f32x4 z = {0.f, 0.f, 0.f, 0.f};
    return __builtin_elementwise_max(a, z);
}
// relu on a packed f16 pair (v_pk_max_f16); pkrtz(neg) stays <=0 so
// relu-after-pack == pack-after-relu.
__device__ inline unsigned int relu_pk(unsigned int u) {
    fp16x2 h = __builtin_bit_cast(fp16x2, u);
    fp16x2 z = {(__fp16)0.f, (__fp16)0.f};
    h = __builtin_elementwise_max(h, z);
    return __builtin_bit_cast(unsigned int, h);
}
__device__ inline unsigned int pk_rtn(float lo, float hi) {
    unsigned short l = __builtin_bit_cast(unsigned short, (_Float16)lo);
    unsigned short h = __builtin_bit_cast(unsigned short, (_Float16)hi);
    return ((unsigned int)h << 16) | (unsigned int)l;
}

// ---- setup: weight fragments (3 timesteps), scaled b1/W2, q->qout copy ----
__global__ __launch_bounds__(256) void epn_frag_kernel(
    const float* __restrict__ W0,   // [3][80][64]
    const float* __restrict__ W1,   // [3][64][64]
    const float* __restrict__ b1,   // [3][64]
    const float* __restrict__ W2,   // [3][64]
    const float* __restrict__ qin,
    uint4* __restrict__ ae,         // [3][4][64]  K=32 e-term A-frags (z=u-q, w=v-q wts)
    uint4* __restrict__ fw0a,       // [3][4][64]  K=32 A-frags (W0 rows 0..31, /16)
    uint4* __restrict__ fw0b,       // [3][4][64]  K=32 A-frags (W0 rows 32..63, /16)
    uint4* __restrict__ fw1,        // [3][8][64]  sigma-permuted K=32 A-frags
    float* __restrict__ b1s,        // [3][64] = b1/16
    float* __restrict__ w2s,        // [3][64] = 16*W2
    float* __restrict__ qout)
{
    const int idx = blockIdx.x * 256 + threadIdx.x;   // grid 17 -> 4352
    if (idx < 768) {                                  // ae: (ts, t, lane)
        int lane = idx & 63, t = (idx >> 6) & 3, ts = idx >> 8;
        int nl = lane & 15, qd = lane >> 4;
        float v[4];
        #pragma unroll
        for (int j = 0; j < 4; ++j)
            v[j] = W0[ts * 80 * 64 + (64 + qd * 4 + j) * 64 + t * 16 + nl] * 0.0625f;
        unsigned int wzu = 0u, wzv = 0u;
        if (qd == 0) {   // q slots: lo-elem pairs f16(q/16), hi-elem pairs residual
            float wqu = W0[ts * 80 * 64 + 63 * 64 + t * 16 + nl];
            float wqv = W0[ts * 80 * 64 + 31 * 64 + t * 16 + nl];
            wzu = pk_rtn(wqu, wqu * 0.0625f);
            wzv = pk_rtn(wqv, wqv * 0.0625f);
        }
        uint4 p;
        p.x = pkrtz(v[0], v[1]); p.y = pkrtz(v[2], v[3]);
        p.z = wzu; p.w = wzv;
        ae[idx] = p;
    } else if (idx < 2304) {                          // fw1: (ts, sp, t2, lane)
        int i2 = idx - 768;
        int lane = i2 & 63, t2 = (i2 >> 6) & 3, sp = (i2 >> 8) & 1, ts = i2 >> 9;
        int nl = lane & 15, qd = lane >> 4;
        float v[8];
        #pragma unroll
        for (int j = 0; j < 8; ++j) {
            int k = (2 * (j >> 2) + sp) * 16 + qd * 4 + (j & 3);   // sigma-permuted k
            v[j] = W1[ts * 64 * 64 + k * 64 + t2 * 16 + nl];
        }
        uint4 p;
        p.x = pkrtz(v[0], v[1]); p.y = pkrtz(v[2], v[3]);
        p.z = pkrtz(v[4], v[5]); p.w = pkrtz(v[6], v[7]);
        fw1[(ts * 8 + sp * 4 + t2) * 64 + lane] = p;
    } else if (idx < 2496) {                          // b1s / w2s
        int i2 = idx - 2304;
        b1s[i2] = b1[i2] * 0.0625f;
        w2s[i2] = W2[i2] * 16.f;
    } else if (idx < 2752) {                          // q -> qout
        int i4 = idx - 2496;
        *(float4*)&qout[i4 * 4] = *(const float4*)&qin[i4 * 4];
    } else if (idx < 4288) {                          // fw0a / fw0b
        int i2 = idx - 2752;                          // 0..1535
        int isB = (i2 >= 768);
        if (isB) i2 -= 768;
        int lane = i2 & 63, t = (i2 >> 6) & 3, ts = i2 >> 8;
        int nl = lane & 15, qd = lane >> 4;
        int rbase = isB ? 32 : 0;
        float v[8];
        #pragma unroll
        for (int j = 0; j < 8; ++j)
            v[j] = W0[ts * 80 * 64 + (rbase + qd * 8 + j) * 64 + t * 16 + nl] * 0.0625f;
        uint4 p;
        p.x = pkrtz(v[0], v[1]); p.y = pkrtz(v[2], v[3]);
        p.z = pkrtz(v[4], v[5]); p.w = pkrtz(v[6], v[7]);
        (isB ? fw0b : fw0a)[(ts * 4 + t) * 64 + lane] = p;
    }
}

// --- per-timestep projection: P,Q (fp32, +b0, /16) + aH (h only, f16) + q snapshot ---
__global__ __launch_bounds__(256) void epn_proj_kernel(
    const float* __restrict__ h, const float* __restrict__ qcur,
    const float* __restrict__ W0, const float* __restrict__ b0,
    float* __restrict__ P, float* __restrict__ Q,
    _Float16* __restrict__ aH, float* __restrict__ qsn)
{
    __shared__ float sa[4][32];
    const int tid = threadIdx.x;
    const int base = blockIdx.x * 4;
    if (tid < 128) {
        int la = tid >> 5, c = tid & 31, atom = base + la;
        sa[la][c] = (c < 31) ? h[atom * 31 + c] : qcur[atom];
    }
    __syncthreads();
    if (tid < 128) {   // h snapshot only; q slot zeroed (f16 range!)
        int la = tid >> 5, c = tid & 31;
        aH[(base + la) * 32 + c] = (c < 31) ? (_Float16)sa[la][c] : (_Float16)0.f;
    }
    if (tid < 4) qsn[base + tid] = sa[tid][31];   // fp32 q snapshot
    const int la = tid >> 6, m = tid & 63, atom = base + la;
    float accP = b0[m], accQ = b0[m];             // b0 in BOTH: each is a C-init
    #pragma unroll
    for (int c = 0; c < 32; ++c) {
        float av = sa[la][c];
        accP = fmaf(av, W0[c * 64 + m], accP);
        accQ = fmaf(av, W0[(32 + c) * 64 + m], accQ);
    }
    P[atom * 64 + m] = accP * 0.0625f;
    Q[atom * 64 + m] = accQ * 0.0625f;
}

// ---------------- main pair kernel: grid dim3(16, 64), 4 blocks/CU ----------------
__global__ __launch_bounds__(256, 4) void epn_main_kernel(
    const float* __restrict__ e, const float* __restrict__ mask,
    const float* __restrict__ Pg, const float* __restrict__ Qg,
    const _Float16* __restrict__ aH, const float* __restrict__ qsn,
    const uint4* __restrict__ aeg,       // [4][64]
    const uint4* __restrict__ fragW0a,   // [4][64]
    const uint4* __restrict__ fragW0b,   // [4][64]
    const uint4* __restrict__ fragW1,    // [8][64] (sp*4+t2 major)
    const float* __restrict__ b1s, const float* __restrict__ w2s,
    float* __restrict__ qout)
{
    __shared__ float sPi[16][64], sQi[16][64];   // i-side C-inits (broadcast reads)
    __shared__ _Float16 sa[64][40];              // h_j f16, stride 40 (16B-aligned)
    __shared__ uint4 sW0a[4][64], sW0b[4][64];   // h_j-term A-frags (per-lane b128)
    __shared__ float sb1[64], sw2[64], sqj[64];

    const int tid  = threadIdx.x;
    const int lane = tid & 63;
    const int wv   = tid >> 6;
    const int nl   = lane & 15;
    const int qd   = lane >> 4;
    const int i0   = blockIdx.y * 16;    // 64 i-tiles
    const int jb   = blockIdx.x * 64;    // 16 j-blocks, each walks 4 j-tiles

    // stage everything ONCE (no per-step restaging, no loop barriers)
    const int sr = tid >> 4, sc4 = (tid & 15) * 4;
    *(float4*)&sPi[sr][sc4] = *(const float4*)&Pg[(i0 + sr) * 64 + sc4];
    *(float4*)&sQi[sr][sc4] = *(const float4*)&Qg[(i0 + sr) * 64 + sc4];
    {
        const int atom = tid >> 2, seg = (tid & 3) * 8;
        *(uint4*)&sa[atom][seg] = *(const uint4*)&aH[(jb + atom) * 32 + seg];
    }
    sW0a[tid >> 6][tid & 63] = fragW0a[tid];
    sW0b[tid >> 6][tid & 63] = fragW0b[tid];
    if (tid < 64) { sb1[tid] = b1s[tid]; sw2[tid] = w2s[tid]; sqj[tid] = qsn[jb + tid]; }

    // weight frags in registers (48 VGPRs persistent)
    uint4 aef[4], w1r[8];
    #pragma unroll
    for (int t = 0; t < 4; ++t) aef[t] = aeg[t * 64 + lane];
    #pragma unroll
    for (int i = 0; i < 8; ++i) w1r[i] = fragW1[i * 64 + lane];

    // e/mask prefetch for (st=0, g=0)
    float4 eP = *(const float4*)(e + ((size_t)(i0 + wv * 4) * Nn + (jb + nl)) * 16 + qd * 4);
    float  mP = mask[(size_t)(i0 + wv * 4) * Nn + jb + nl];

    float sacc[4] = {0.f, 0.f, 0.f, 0.f};

    __syncthreads();

    for (int st = 0; st < 4; ++st) {
        // B-frag of h_j for this j-tile: B[k=qd*8+j, n=nl]
        const half8 BaH = *(const half8*)&sa[st * 16 + nl][qd * 8];
        // q_j hi/lo pair (k=4,5 for u-dir / k=6,7 for v-dir on the B side)
        const float qv  = sqj[st * 16 + nl];
        const float qh  = (float)(_Float16)(qv * 0.0625f);
        const float qlo = fmaf(qh, -16.f, qv);
        const unsigned int qpk = pk_rtn(qh, qlo);

        #pragma unroll
        for (int g = 0; g < 4; ++g) {
            const int il = wv * 4 + g;
            float4 ec = eP; float mc = mP;
            // prefetch next (st, g)
            if (g < 3) {
                const size_t off = (size_t)(i0 + il + 1) * Nn + (jb + st * 16 + nl);
                eP = *(const float4*)(e + off * 16 + qd * 4);
                mP = mask[off];
            } else if (st < 3) {
                const size_t off = (size_t)(i0 + wv * 4) * Nn + (jb + (st + 1) * 16 + nl);
                eP = *(const float4*)(e + off * 16 + qd * 4);
                mP = mask[off];
            }

            const unsigned int pk01 = pkrtz(ec.x, ec.y);
            const unsigned int pk23 = pkrtz(ec.z, ec.w);
            uint4v beu = {pk01, pk23, qpk, 0u};   // u-dir: q hits A word z (k=4,5)
            uint4v bev = {pk01, pk23, 0u, qpk};   // v-dir: q hits A word w (k=6,7)
            const half8 Beu = __builtin_bit_cast(half8, beu);
            const half8 Bev = __builtin_bit_cast(half8, bev);

            // ---- U pass (ij): h_j-term K=32 (C-init = Pi), then e+q-term ----
            uint4v bu[2];
            #pragma unroll
            for (int t = 0; t < 4; ++t) {
                const int off = t * 16 + qd * 4;
                f32x4 Ci = *(const f32x4*)&sPi[il][off];    // broadcast
                const uint4 w0b = sW0b[t][lane];            // per-lane, conflict-free
                f32x4 Eu = MFMAH32(__builtin_bit_cast(half8, aef[t]), Beu,
                           MFMAH32(__builtin_bit_cast(half8, w0b), BaH, Ci));
                const int sp = t & 1, b = (t >> 1) * 2;
                bu[sp][b]     = relu_pk(pkrtz(Eu[0], Eu[1]));
                bu[sp][b + 1] = relu_pk(pkrtz(Eu[2], Eu[3]));
            }

            // ---- V pass (ji): h_j-term K=32 (C-init = Qi), then e+q-term ----
            uint4v bv[2];
            #pragma unroll
            for (int t = 0; t < 4; ++t) {
                const int off = t * 16 + qd * 4;
                f32x4 Cq = *(const f32x4*)&sQi[il][off];    // broadcast
                const uint4 w0a = sW0a[t][lane];            // per-lane, conflict-free
                f32x4 Ev = MFMAH32(__builtin_bit_cast(half8, aef[t]), Bev,
                           MFMAH32(__builtin_bit_cast(half8, w0a), BaH, Cq));
                const int sp = t & 1, b = (t >> 1) * 2;
                bv[sp][b]     = relu_pk(pkrtz(Ev[0], Ev[1]));
                bv[sp][b + 1] = relu_pk(pkrtz(Ev[2], Ev[3]));
            }

            // layer 2 (C-init = b1/16) + epilogue (16x folded into w2s)
            f32x4 s4 = {0.f, 0.f, 0.f, 0.f};
            #pragma unroll
            for (int t2 = 0; t2 < 4; ++t2) {
                f32x4 binit = *(const f32x4*)&sb1[t2 * 16 + qd * 4];
                f32x4 w2q   = *(const f32x4*)&sw2[t2 * 16 + qd * 4];
                f32x4 x = MFMAH32(__builtin_bit_cast(half8, w1r[t2]),
                                  __builtin_bit_cast(half8, bu[0]), binit);
                x = MFMAH32(__builtin_bit_cast(half8, w1r[4 + t2]),
                            __builtin_bit_cast(half8, bu[1]), x);
                f32x4 y = MFMAH32(__builtin_bit_cast(half8, w1r[t2]),
                                  __builtin_bit_cast(half8, bv[0]), binit);
                y = MFMAH32(__builtin_bit_cast(half8, w1r[4 + t2]),
                            __builtin_bit_cast(half8, bv[1]), y);
                s4 += (max0(x) - max0(y)) * w2q;
            }

            sacc[g] += ((s4[0] + s4[1]) + (s4[2] + s4[3])) * mc;
        }
    }

    // one reduction + atomic per i-atom (4 j-tiles folded in registers)
    #pragma unroll
    for (int g = 0; g < 4; ++g) {
        float s = sacc[g];
        s += __shfl_xor(s, 1);
        s += __shfl_xor(s, 2);
        s += __shfl_xor(s, 4);
        s += __shfl_xor(s, 8);
        s += __shfl_xor(s, 16);
        s += __shfl_xor(s, 32);
        if (lane == 0) atomicAdd(&qout[i0 + wv * 4 + g], s);
    }
}

extern "C" void kernel_launch(void* const* d_in, const int* in_sizes, int n_in,
                              void* d_out, int out_size, void* d_ws, size_t ws_size,
                              hipStream_t stream) {
    const float* h    = (const float*)d_in[0];
    const float* e    = (const float*)d_in[1];
    const float* q    = (const float*)d_in[2];
    const float* mask = (const float*)d_in[3];
    const float* W0   = (const float*)d_in[5];
    const float* b0   = (const float*)d_in[6];
    const float* W1   = (const float*)d_in[7];
    const float* b1   = (const float*)d_in[8];
    const float* W2   = (const float*)d_in[9];
    // d_in[10] = b2 cancels in the antisymmetrization

    float* qout = (float*)d_out;
    char*  ws   = (char*)d_ws;
    float*    Pws  = (float*)(ws);                           // 256 KB
    float*    Qws  = (float*)(ws + 256 * 1024);              // 256 KB
    _Float16* aH   = (_Float16*)(ws + 512 * 1024);           // 64 KB
    float*    qsn  = (float*)(ws + 576 * 1024);              // 4 KB
    char*     fb   = ws + 580 * 1024;
    uint4*    ae   = (uint4*)(fb);                           // 12 KB
    uint4*    fw0a = (uint4*)(fb + 12288);                   // 12 KB
    uint4*    fw0b = (uint4*)(fb + 24576);                   // 12 KB
    uint4*    fw1  = (uint4*)(fb + 36864);                   // 24 KB
    float*    b1s  = (float*)(fb + 61440);                   // 768 B
    float*    w2s  = (float*)(fb + 62208);                   // 768 B

    epn_frag_kernel<<<17, 256, 0, stream>>>(W0, W1, b1, W2, q,
                                            ae, fw0a, fw0b, fw1, b1s, w2s, qout);
    for (int t = 0; t < 3; ++t) {
        epn_proj_kernel<<<256, 256, 0, stream>>>(h, qout, W0 + t * 80 * 64, b0 + t * 64,
                                                 Pws, Qws, aH, qsn);
        epn_main_kernel<<<dim3(16, 64), 256, 0, stream>>>(
            e, mask, Pws, Qws, aH, qsn,
            ae + (size_t)t * 4 * 64,
            fw0a + (size_t)t * 4 * 64, fw0b + (size_t)t * 4 * 64,
            fw1 + (size_t)t * 8 * 64,
            b1s + t * 64, w2s + t * 64, qout);
    }
}

// Round 6
// 756.464 us; speedup vs baseline: 1.6365x; 1.6365x over previous
//
#include <hip/hip_runtime.h>

// EPN_flax, round 15: round-9 kernel (best verified: 235.9us, 64 VGPR, zero
// spill) + two envelope-neutral VALU cuts, both numerically validated by the
// passing round-12 run:
//  (1) pack-then-relu: pkrtz then v_pk_max_f16 replaces f32 max0 + pkrtz
//      (6 -> 4 VALU per t per dir; relu(pkrtz(x)) == pkrtz(relu(x)) since
//      RTZ preserves sign).
//  (2) register accumulation sacc[4] across the 4 j-steps: shuffle-reduce +
//      atomic once per i-atom instead of once per (j-step, i-atom) — removes
//      3/4 of the shfl chains (LDS-pipe ops on CDNA) and 48/64 atomics/block.
// Lesson from rounds 10-14: at (256,4) this toolchain gives ~64 arch + ~64
// acc VGPRs; any structure with more live state (MFMA-folded j-side) spills
// to scratch (WRITE_SIZE 40-680 MB) and loses. Round 9's structure fits.

constexpr int Nn = 1024;

typedef _Float16 half4 __attribute__((ext_vector_type(4)));
typedef _Float16 half8 __attribute__((ext_vector_type(8)));
typedef __fp16   fp16x2 __attribute__((ext_vector_type(2)));
typedef float    f32x4 __attribute__((ext_vector_type(4)));
typedef unsigned int uint2v __attribute__((ext_vector_type(2)));
typedef unsigned int uint4v __attribute__((ext_vector_type(4)));

#define MFMAH32(A, B, C) __builtin_amdgcn_mfma_f32_16x16x32_f16(A, B, C, 0, 0, 0)

#if __has_builtin(__builtin_amdgcn_mfma_f32_16x16x16f16)
__device__ inline f32x4 mfma16(half4 a, half4 b, f32x4 c) {
    return __builtin_amdgcn_mfma_f32_16x16x16f16(a, b, c, 0, 0, 0);
}
#else
__device__ inline f32x4 mfma16(half4 a, half4 b, f32x4 c) {
    // zero-padded fallback: features in slots j<4 of each quad's k-range
    half8 a8 = {a[0], a[1], a[2], a[3], (_Float16)0, (_Float16)0, (_Float16)0, (_Float16)0};
    half8 b8 = {b[0], b[1], b[2], b[3], (_Float16)0, (_Float16)0, (_Float16)0, (_Float16)0};
    return MFMAH32(a8, b8, c);
}
#endif

__device__ inline unsigned int pkrtz(float a, float b) {
    fp16x2 r = __builtin_amdgcn_cvt_pkrtz(a, b);
    return __builtin_bit_cast(unsigned int, r);
}
__device__ inline f32x4 max0(f32x4 a) {
    f32x4 z = {0.f, 0.f, 0.f, 0.f};
    return __builtin_elementwise_max(a, z);
}
// relu on a packed f16 pair (v_pk_max_f16); pkrtz(neg) stays <=0 so
// relu-after-pack == pack-after-relu.
__device__ inline unsigned int relu_pk(unsigned int u) {
    fp16x2 h = __builtin_bit_cast(fp16x2, u);
    fp16x2 z = {(__fp16)0.f, (__fp16)0.f};
    h = __builtin_elementwise_max(h, z);
    return __builtin_bit_cast(unsigned int, h);
}

// ---- setup: weight fragments (3 timesteps), scaled b1/W2, q->qout copy ----
__global__ __launch_bounds__(256) void epn_frag_kernel(
    const float* __restrict__ W0,   // [3][80][64]
    const float* __restrict__ W1,   // [3][64][64]
    const float* __restrict__ b1,   // [3][64]
    const float* __restrict__ W2,   // [3][64]
    const float* __restrict__ qin,
    uint2v* __restrict__ fw0e,      // [3][4][64]  K=16 A-frags
    uint4*  __restrict__ fw1,       // [3][8][64]  sigma-permuted K=32 A-frags
    float*  __restrict__ b1s,       // [3][64] = b1/16
    float*  __restrict__ w2s,       // [3][64] = 16*W2
    float*  __restrict__ qout)
{
    const int idx = blockIdx.x * 256 + threadIdx.x;   // grid 11 -> 2816
    if (idx < 768) {                                  // fw0e: (ts, t, lane)
        int lane = idx & 63, t = (idx >> 6) & 3, ts = idx >> 8;
        int nl = lane & 15, qd = lane >> 4;
        float v[4];
        #pragma unroll
        for (int j = 0; j < 4; ++j)
            v[j] = W0[ts * 80 * 64 + (64 + qd * 4 + j) * 64 + t * 16 + nl] * 0.0625f;
        uint2v p = {pkrtz(v[0], v[1]), pkrtz(v[2], v[3])};
        fw0e[idx] = p;
    } else if (idx < 2304) {                          // fw1: (ts, sp, t2, lane)
        int i2 = idx - 768;
        int lane = i2 & 63, t2 = (i2 >> 6) & 3, sp = (i2 >> 8) & 1, ts = i2 >> 9;
        int nl = lane & 15, qd = lane >> 4;
        float v[8];
        #pragma unroll
        for (int j = 0; j < 8; ++j) {
            int k = (2 * (j >> 2) + sp) * 16 + qd * 4 + (j & 3);   // sigma-permuted k
            v[j] = W1[ts * 64 * 64 + k * 64 + t2 * 16 + nl];
        }
        uint4 p;
        p.x = pkrtz(v[0], v[1]); p.y = pkrtz(v[2], v[3]);
        p.z = pkrtz(v[4], v[5]); p.w = pkrtz(v[6], v[7]);
        fw1[(ts * 8 + sp * 4 + t2) * 64 + lane] = p;
    } else if (idx < 2496) {                          // b1s / w2s
        int i2 = idx - 2304;
        b1s[i2] = b1[i2] * 0.0625f;
        w2s[i2] = W2[i2] * 16.f;
    } else if (idx < 2752) {                          // q -> qout
        int i4 = idx - 2496;
        *(float4*)&qout[i4 * 4] = *(const float4*)&qin[i4 * 4];
    }
}

// ---------------- per-timestep projection: P,Q (fp32, pre-scaled 1/16) ----------------
__global__ __launch_bounds__(256) void epn_proj_kernel(
    const float* __restrict__ h, const float* __restrict__ qcur,
    const float* __restrict__ W0, const float* __restrict__ b0,
    float* __restrict__ P, float* __restrict__ Q)
{
    __shared__ float sa[4][32];
    const int tid = threadIdx.x;
    const int base = blockIdx.x * 4;
    if (tid < 128) {
        int la = tid >> 5, c = tid & 31, atom = base + la;
        sa[la][c] = (c < 31) ? h[atom * 31 + c] : qcur[atom];
    }
    __syncthreads();
    const int la = tid >> 6, m = tid & 63, atom = base + la;
    float accP = b0[m], accQ = 0.f;
    #pragma unroll
    for (int c = 0; c < 32; ++c) {
        float av = sa[la][c];
        accP = fmaf(av, W0[c * 64 + m], accP);
        accQ = fmaf(av, W0[(32 + c) * 64 + m], accQ);
    }
    P[atom * 64 + m] = accP * 0.0625f;
    Q[atom * 64 + m] = accQ * 0.0625f;
}

// ---------------- main pair kernel: grid dim3(16, 64) ----------------
__global__ __launch_bounds__(256, 4) void epn_main_kernel(
    const float* __restrict__ e, const float* __restrict__ mask,
    const float* __restrict__ Pg, const float* __restrict__ Qg,
    const uint2v* __restrict__ fragW0e,  // [4][64]
    const uint4*  __restrict__ fragW1,   // [8][64] (sp*4+t2 major)
    const float* __restrict__ b1s, const float* __restrict__ w2s,
    float* __restrict__ qout)
{
    __shared__ float sPi[16][68], sQi[16][68];   // i-side, staged once
    __shared__ float sPj[16][68], sQj[16][68];   // j-side, re-staged per step
    __shared__ float sb1[64], sw2[64];

    const int tid  = threadIdx.x;
    const int lane = tid & 63;
    const int wv   = tid >> 6;
    const int nl   = lane & 15;
    const int qd   = lane >> 4;
    const int i0   = blockIdx.y * 16;    // 64 i-tiles
    const int jb   = blockIdx.x * 64;    // 16 j-blocks, each walks 4 j-tiles

    // stage i-side P/Q + j-side step 0 (one float4 per thread per array)
    const int sr = tid >> 4, sc4 = (tid & 15) * 4;
    *(float4*)&sPi[sr][sc4] = *(const float4*)&Pg[(i0 + sr) * 64 + sc4];
    *(float4*)&sQi[sr][sc4] = *(const float4*)&Qg[(i0 + sr) * 64 + sc4];
    *(float4*)&sPj[sr][sc4] = *(const float4*)&Pg[(jb + sr) * 64 + sc4];
    *(float4*)&sQj[sr][sc4] = *(const float4*)&Qg[(jb + sr) * 64 + sc4];
    if (tid < 64) { sb1[tid] = b1s[tid]; sw2[tid] = w2s[tid]; }

    // weight frags in registers
    uint2v Aw0e[4];
    #pragma unroll
    for (int t = 0; t < 4; ++t) Aw0e[t] = fragW0e[t * 64 + lane];
    uint4 w1r[8];
    #pragma unroll
    for (int i = 0; i < 8; ++i) w1r[i] = fragW1[i * 64 + lane];

    // e/mask prefetch for gs=0
    float4 eP = *(const float4*)(e + ((size_t)(i0 + wv * 4) * Nn + (jb + nl)) * 16 + qd * 4);
    float  mP = mask[(size_t)(i0 + wv * 4) * Nn + jb + nl];

    float sacc[4] = {0.f, 0.f, 0.f, 0.f};

    __syncthreads();

    for (int st = 0; st < 4; ++st) {
        // issue next step's j-side loads now (land during compute)
        float4 pjr, qjr;
        if (st < 3) {
            int jatom = jb + (st + 1) * 16 + sr;
            pjr = *(const float4*)&Pg[jatom * 64 + sc4];
            qjr = *(const float4*)&Qg[jatom * 64 + sc4];
        }

        #pragma unroll
        for (int g = 0; g < 4; ++g) {
            const int il = wv * 4 + g;
            float4 ec = eP; float mc = mP;
            const int gs = st * 4 + g;
            if (gs < 15) {   // prefetch next (step, group)
                int ngs = gs + 1, nst = ngs >> 2, ng = ngs & 3;
                int nil = wv * 4 + ng;
                eP = *(const float4*)(e + ((size_t)(i0 + nil) * Nn + (jb + nst * 16 + nl)) * 16 + qd * 4);
                mP = mask[(size_t)(i0 + nil) * Nn + jb + nst * 16 + nl];
            }

            uint2v ep = {pkrtz(ec.x, ec.y), pkrtz(ec.z, ec.w)};
            half4 Be = __builtin_bit_cast(half4, ep);

            // layer 1 (C-init = Pi+Qj / Pj+Qi) -> pack -> pk-relu -> L2 B-frags
            uint4v bu[2], bv[2];
            #pragma unroll
            for (int t = 0; t < 4; ++t) {
                const int off = t * 16 + qd * 4;
                f32x4 Pi = *(const f32x4*)&sPi[il][off];    // wave-uniform broadcast
                f32x4 Qi = *(const f32x4*)&sQi[il][off];
                f32x4 Qj = *(const f32x4*)&sQj[nl][off];    // per-lane
                f32x4 Pj = *(const f32x4*)&sPj[nl][off];
                half4 aw = __builtin_bit_cast(half4, Aw0e[t]);
                f32x4 Eu = mfma16(aw, Be, Pi + Qj);
                f32x4 Ev = mfma16(aw, Be, Pj + Qi);
                const int sp = t & 1, b = (t >> 1) * 2;
                bu[sp][b]     = relu_pk(pkrtz(Eu[0], Eu[1]));
                bu[sp][b + 1] = relu_pk(pkrtz(Eu[2], Eu[3]));
                bv[sp][b]     = relu_pk(pkrtz(Ev[0], Ev[1]));
                bv[sp][b + 1] = relu_pk(pkrtz(Ev[2], Ev[3]));
            }

            // layer 2 (C-init = b1/16) + epilogue (16x folded into w2s)
            f32x4 s4 = {0.f, 0.f, 0.f, 0.f};
            #pragma unroll
            for (int t2 = 0; t2 < 4; ++t2) {
                f32x4 binit = *(const f32x4*)&sb1[t2 * 16 + qd * 4];
                f32x4 w2q   = *(const f32x4*)&sw2[t2 * 16 + qd * 4];
                half8 w1a = __builtin_bit_cast(half8, w1r[t2]);
                half8 w1b = __builtin_bit_cast(half8, w1r[4 + t2]);
                f32x4 x = MFMAH32(w1a, __builtin_bit_cast(half8, bu[0]), binit);
                x = MFMAH32(w1b, __builtin_bit_cast(half8, bu[1]), x);
                f32x4 y = MFMAH32(w1a, __builtin_bit_cast(half8, bv[0]), binit);
                y = MFMAH32(w1b, __builtin_bit_cast(half8, bv[1]), y);
                s4 += (max0(x) - max0(y)) * w2q;
            }

            sacc[g] += ((s4[0] + s4[1]) + (s4[2] + s4[3])) * mc;
        }

        if (st < 3) {   // swap in next j-tile
            __syncthreads();
            *(float4*)&sPj[sr][sc4] = pjr;
            *(float4*)&sQj[sr][sc4] = qjr;
            __syncthreads();
        }
    }

    // one reduction + atomic per i-atom (4 j-steps folded in registers)
    #pragma unroll
    for (int g = 0; g < 4; ++g) {
        float s = sacc[g];
        s += __shfl_xor(s, 1);
        s += __shfl_xor(s, 2);
        s += __shfl_xor(s, 4);
        s += __shfl_xor(s, 8);
        s += __shfl_xor(s, 16);
        s += __shfl_xor(s, 32);
        if (lane == 0) atomicAdd(&qout[i0 + wv * 4 + g], s);
    }
}

extern "C" void kernel_launch(void* const* d_in, const int* in_sizes, int n_in,
                              void* d_out, int out_size, void* d_ws, size_t ws_size,
                              hipStream_t stream) {
    const float* h    = (const float*)d_in[0];
    const float* e    = (const float*)d_in[1];
    const float* q    = (const float*)d_in[2];
    const float* mask = (const float*)d_in[3];
    const float* W0   = (const float*)d_in[5];
    const float* b0   = (const float*)d_in[6];
    const float* W1   = (const float*)d_in[7];
    const float* b1   = (const float*)d_in[8];
    const float* W2   = (const float*)d_in[9];
    // d_in[10] = b2 cancels in the antisymmetrization

    float* qout = (float*)d_out;
    char*  ws   = (char*)d_ws;
    float*  Pws  = (float*)(ws);                        // 256 KB
    float*  Qws  = (float*)(ws + 256 * 1024);           // 256 KB
    uint2v* fw0e = (uint2v*)(ws + 512 * 1024);          // 6 KB
    uint4*  fw1  = (uint4*)(ws + 512 * 1024 + 6144);    // 24 KB
    float*  b1s  = (float*)(ws + 512 * 1024 + 30720);   // 768 B
    float*  w2s  = (float*)(ws + 512 * 1024 + 31488);   // 768 B

    epn_frag_kernel<<<11, 256, 0, stream>>>(W0, W1, b1, W2, q, fw0e, fw1, b1s, w2s, qout);
    for (int t = 0; t < 3; ++t) {
        epn_proj_kernel<<<256, 256, 0, stream>>>(h, qout, W0 + t * 80 * 64, b0 + t * 64,
                                                 Pws, Qws);
        epn_main_kernel<<<dim3(16, 64), 256, 0, stream>>>(
            e, mask, Pws, Qws,
            fw0e + (size_t)t * 4 * 64, fw1 + (size_t)t * 8 * 64,
            b1s + t * 64, w2s + t * 64, qout);
    }
}

// Round 8
// 237.046 us; speedup vs baseline: 5.2224x; 3.1912x over previous
//
#include <hip/hip_runtime.h>

// EPN_flax, round 17: round-9 kernel VERBATIM (7 rounds of evidence: any edit
// to the main kernel's dataflow tips the 64-VGPR bucket into hot-loop scratch
// spill — r11 679MB, r12 40MB, r14 445MB, r15 394MB WRITE_SIZE; and grid-wide
// coop fusion breaks numerically under graph capture, r16). The one remaining
// safe target: the proj kernel was latency-bound (~20us each, ~60us of the
// 236.7 total): 64 serial scalar W0 loads per thread at 1 block/CU. Fix: stage
// W0's 64x64 block into LDS (16 KB, coalesced float4), run the IDENTICAL FMA
// sequence from LDS (sW[c][m]: consecutive-m lanes = 2-way = free; bitwise
// identical accumulation). Main kernel untouched; absmax must stay 1024.

constexpr int Nn = 1024;

typedef _Float16 half4 __attribute__((ext_vector_type(4)));
typedef _Float16 half8 __attribute__((ext_vector_type(8)));
typedef __fp16   fp16x2 __attribute__((ext_vector_type(2)));
typedef float    f32x4 __attribute__((ext_vector_type(4)));
typedef unsigned int uint2v __attribute__((ext_vector_type(2)));
typedef unsigned int uint4v __attribute__((ext_vector_type(4)));

#define MFMAH32(A, B, C) __builtin_amdgcn_mfma_f32_16x16x32_f16(A, B, C, 0, 0, 0)

#if __has_builtin(__builtin_amdgcn_mfma_f32_16x16x16f16)
__device__ inline f32x4 mfma16(half4 a, half4 b, f32x4 c) {
    return __builtin_amdgcn_mfma_f32_16x16x16f16(a, b, c, 0, 0, 0);
}
#else
__device__ inline f32x4 mfma16(half4 a, half4 b, f32x4 c) {
    // zero-padded fallback: features in slots j<4 of each quad's k-range
    half8 a8 = {a[0], a[1], a[2], a[3], (_Float16)0, (_Float16)0, (_Float16)0, (_Float16)0};
    half8 b8 = {b[0], b[1], b[2], b[3], (_Float16)0, (_Float16)0, (_Float16)0, (_Float16)0};
    return MFMAH32(a8, b8, c);
}
#endif

__device__ inline unsigned int pkrtz(float a, float b) {
    fp16x2 r = __builtin_amdgcn_cvt_pkrtz(a, b);
    return __builtin_bit_cast(unsigned int, r);
}
__device__ inline f32x4 max0(f32x4 a) {
    f32x4 z = {0.f, 0.f, 0.f, 0.f};
    return __builtin_elementwise_max(a, z);
}

// ---- setup: weight fragments (3 timesteps), scaled b1/W2, q->qout copy ----
__global__ __launch_bounds__(256) void epn_frag_kernel(
    const float* __restrict__ W0,   // [3][80][64]
    const float* __restrict__ W1,   // [3][64][64]
    const float* __restrict__ b1,   // [3][64]
    const float* __restrict__ W2,   // [3][64]
    const float* __restrict__ qin,
    uint2v* __restrict__ fw0e,      // [3][4][64]  K=16 A-frags
    uint4*  __restrict__ fw1,       // [3][8][64]  sigma-permuted K=32 A-frags
    float*  __restrict__ b1s,       // [3][64] = b1/16
    float*  __restrict__ w2s,       // [3][64] = 16*W2
    float*  __restrict__ qout)
{
    const int idx = blockIdx.x * 256 + threadIdx.x;   // grid 11 -> 2816
    if (idx < 768) {                                  // fw0e: (ts, t, lane)
        int lane = idx & 63, t = (idx >> 6) & 3, ts = idx >> 8;
        int nl = lane & 15, qd = lane >> 4;
        float v[4];
        #pragma unroll
        for (int j = 0; j < 4; ++j)
            v[j] = W0[ts * 80 * 64 + (64 + qd * 4 + j) * 64 + t * 16 + nl] * 0.0625f;
        uint2v p = {pkrtz(v[0], v[1]), pkrtz(v[2], v[3])};
        fw0e[idx] = p;
    } else if (idx < 2304) {                          // fw1: (ts, sp, t2, lane)
        int i2 = idx - 768;
        int lane = i2 & 63, t2 = (i2 >> 6) & 3, sp = (i2 >> 8) & 1, ts = i2 >> 9;
        int nl = lane & 15, qd = lane >> 4;
        float v[8];
        #pragma unroll
        for (int j = 0; j < 8; ++j) {
            int k = (2 * (j >> 2) + sp) * 16 + qd * 4 + (j & 3);   // sigma-permuted k
            v[j] = W1[ts * 64 * 64 + k * 64 + t2 * 16 + nl];
        }
        uint4 p;
        p.x = pkrtz(v[0], v[1]); p.y = pkrtz(v[2], v[3]);
        p.z = pkrtz(v[4], v[5]); p.w = pkrtz(v[6], v[7]);
        fw1[(ts * 8 + sp * 4 + t2) * 64 + lane] = p;
    } else if (idx < 2496) {                          // b1s / w2s
        int i2 = idx - 2304;
        b1s[i2] = b1[i2] * 0.0625f;
        w2s[i2] = W2[i2] * 16.f;
    } else if (idx < 2752) {                          // q -> qout
        int i4 = idx - 2496;
        *(float4*)&qout[i4 * 4] = *(const float4*)&qin[i4 * 4];
    }
}

// ------ per-timestep projection: P,Q (fp32, pre-scaled 1/16), W0 via LDS ------
__global__ __launch_bounds__(256) void epn_proj_kernel(
    const float* __restrict__ h, const float* __restrict__ qcur,
    const float* __restrict__ W0, const float* __restrict__ b0,
    float* __restrict__ P, float* __restrict__ Q)
{
    __shared__ float sW[64][64];   // W0 rows 0..63 (16 KB), coalesced stage
    __shared__ float sa[4][32];
    const int tid = threadIdx.x;
    const int base = blockIdx.x * 4;
    #pragma unroll
    for (int k = 0; k < 4; ++k) {                 // 4096 floats: 4 float4 / thread
        int idx = k * 1024 + tid * 4;
        *(float4*)&sW[idx >> 6][idx & 63] = *(const float4*)&W0[idx];
    }
    if (tid < 128) {
        int la = tid >> 5, c = tid & 31, atom = base + la;
        sa[la][c] = (c < 31) ? h[atom * 31 + c] : qcur[atom];
    }
    __syncthreads();
    const int la = tid >> 6, m = tid & 63, atom = base + la;
    float accP = b0[m], accQ = 0.f;
    #pragma unroll
    for (int c = 0; c < 32; ++c) {                // identical order -> bit-identical
        float av = sa[la][c];
        accP = fmaf(av, sW[c][m], accP);
        accQ = fmaf(av, sW[32 + c][m], accQ);
    }
    P[atom * 64 + m] = accP * 0.0625f;
    Q[atom * 64 + m] = accQ * 0.0625f;
}

// ---------------- main pair kernel: grid dim3(16, 64) ----------------
__global__ __launch_bounds__(256, 4) void epn_main_kernel(
    const float* __restrict__ e, const float* __restrict__ mask,
    const float* __restrict__ Pg, const float* __restrict__ Qg,
    const uint2v* __restrict__ fragW0e,  // [4][64]
    const uint4*  __restrict__ fragW1,   // [8][64] (sp*4+t2 major)
    const float* __restrict__ b1s, const float* __restrict__ w2s,
    float* __restrict__ qout)
{
    __shared__ float sPi[16][68], sQi[16][68];   // i-side, staged once
    __shared__ float sPj[16][68], sQj[16][68];   // j-side, re-staged per step
    __shared__ float sb1[64], sw2[64];

    const int tid  = threadIdx.x;
    const int lane = tid & 63;
    const int wv   = tid >> 6;
    const int nl   = lane & 15;
    const int qd   = lane >> 4;
    const int i0   = blockIdx.y * 16;    // 64 i-tiles
    const int jb   = blockIdx.x * 64;    // 16 j-blocks, each walks 4 j-tiles

    // stage i-side P/Q + j-side step 0 (one float4 per thread per array)
    const int sr = tid >> 4, sc4 = (tid & 15) * 4;
    *(float4*)&sPi[sr][sc4] = *(const float4*)&Pg[(i0 + sr) * 64 + sc4];
    *(float4*)&sQi[sr][sc4] = *(const float4*)&Qg[(i0 + sr) * 64 + sc4];
    *(float4*)&sPj[sr][sc4] = *(const float4*)&Pg[(jb + sr) * 64 + sc4];
    *(float4*)&sQj[sr][sc4] = *(const float4*)&Qg[(jb + sr) * 64 + sc4];
    if (tid < 64) { sb1[tid] = b1s[tid]; sw2[tid] = w2s[tid]; }

    // weight frags in registers
    uint2v Aw0e[4];
    #pragma unroll
    for (int t = 0; t < 4; ++t) Aw0e[t] = fragW0e[t * 64 + lane];
    uint4 w1r[8];
    #pragma unroll
    for (int i = 0; i < 8; ++i) w1r[i] = fragW1[i * 64 + lane];

    // e/mask prefetch for gs=0
    float4 eP = *(const float4*)(e + ((size_t)(i0 + wv * 4) * Nn + (jb + nl)) * 16 + qd * 4);
    float  mP = mask[(size_t)(i0 + wv * 4) * Nn + jb + nl];

    __syncthreads();

    for (int st = 0; st < 4; ++st) {
        // issue next step's j-side loads now (land during compute)
        float4 pjr, qjr;
        if (st < 3) {
            int jatom = jb + (st + 1) * 16 + sr;
            pjr = *(const float4*)&Pg[jatom * 64 + sc4];
            qjr = *(const float4*)&Qg[jatom * 64 + sc4];
        }

        #pragma unroll
        for (int g = 0; g < 4; ++g) {
            const int il = wv * 4 + g;
            float4 ec = eP; float mc = mP;
            const int gs = st * 4 + g;
            if (gs < 15) {   // prefetch next (step, group)
                int ngs = gs + 1, nst = ngs >> 2, ng = ngs & 3;
                int nil = wv * 4 + ng;
                eP = *(const float4*)(e + ((size_t)(i0 + nil) * Nn + (jb + nst * 16 + nl)) * 16 + qd * 4);
                mP = mask[(size_t)(i0 + nil) * Nn + jb + nst * 16 + nl];
            }

            uint2v ep = {pkrtz(ec.x, ec.y), pkrtz(ec.z, ec.w)};
            half4 Be = __builtin_bit_cast(half4, ep);

            // layer 1 (C-init = Pi+Qj / Pj+Qi) -> relu -> pack into L2 B-frags
            uint4v bu[2], bv[2];
            #pragma unroll
            for (int t = 0; t < 4; ++t) {
                const int off = t * 16 + qd * 4;
                f32x4 Pi = *(const f32x4*)&sPi[il][off];    // wave-uniform broadcast
                f32x4 Qi = *(const f32x4*)&sQi[il][off];
                f32x4 Qj = *(const f32x4*)&sQj[nl][off];    // per-lane
                f32x4 Pj = *(const f32x4*)&sPj[nl][off];
                half4 aw = __builtin_bit_cast(half4, Aw0e[t]);
                f32x4 Eu = max0(mfma16(aw, Be, Pi + Qj));
                f32x4 Ev = max0(mfma16(aw, Be, Pj + Qi));
                const int sp = t & 1, b = (t >> 1) * 2;
                bu[sp][b]     = pkrtz(Eu[0], Eu[1]);
                bu[sp][b + 1] = pkrtz(Eu[2], Eu[3]);
                bv[sp][b]     = pkrtz(Ev[0], Ev[1]);
                bv[sp][b + 1] = pkrtz(Ev[2], Ev[3]);
            }

            // layer 2 (C-init = b1/16) + epilogue (16x folded into w2s)
            f32x4 s4 = {0.f, 0.f, 0.f, 0.f};
            #pragma unroll
            for (int t2 = 0; t2 < 4; ++t2) {
                f32x4 binit = *(const f32x4*)&sb1[t2 * 16 + qd * 4];
                f32x4 w2q   = *(const f32x4*)&sw2[t2 * 16 + qd * 4];
                half8 w1a = __builtin_bit_cast(half8, w1r[t2]);
                half8 w1b = __builtin_bit_cast(half8, w1r[4 + t2]);
                f32x4 x = MFMAH32(w1a, __builtin_bit_cast(half8, bu[0]), binit);
                x = MFMAH32(w1b, __builtin_bit_cast(half8, bu[1]), x);
                f32x4 y = MFMAH32(w1a, __builtin_bit_cast(half8, bv[0]), binit);
                y = MFMAH32(w1b, __builtin_bit_cast(half8, bv[1]), y);
                s4 += (max0(x) - max0(y)) * w2q;
            }

            float s = ((s4[0] + s4[1]) + (s4[2] + s4[3])) * mc;
            s += __shfl_xor(s, 1);
            s += __shfl_xor(s, 2);
            s += __shfl_xor(s, 4);
            s += __shfl_xor(s, 8);
            s += __shfl_xor(s, 16);
            s += __shfl_xor(s, 32);
            if (lane == 0) atomicAdd(&qout[i0 + il], s);
        }

        if (st < 3) {   // swap in next j-tile
            __syncthreads();
            *(float4*)&sPj[sr][sc4] = pjr;
            *(float4*)&sQj[sr][sc4] = qjr;
            __syncthreads();
        }
    }
}

extern "C" void kernel_launch(void* const* d_in, const int* in_sizes, int n_in,
                              void* d_out, int out_size, void* d_ws, size_t ws_size,
                              hipStream_t stream) {
    const float* h    = (const float*)d_in[0];
    const float* e    = (const float*)d_in[1];
    const float* q    = (const float*)d_in[2];
    const float* mask = (const float*)d_in[3];
    const float* W0   = (const float*)d_in[5];
    const float* b0   = (const float*)d_in[6];
    const float* W1   = (const float*)d_in[7];
    const float* b1   = (const float*)d_in[8];
    const float* W2   = (const float*)d_in[9];
    // d_in[10] = b2 cancels in the antisymmetrization

    float* qout = (float*)d_out;
    char*  ws   = (char*)d_ws;
    float*  Pws  = (float*)(ws);                        // 256 KB
    float*  Qws  = (float*)(ws + 256 * 1024);           // 256 KB
    uint2v* fw0e = (uint2v*)(ws + 512 * 1024);          // 6 KB
    uint4*  fw1  = (uint4*)(ws + 512 * 1024 + 6144);    // 24 KB
    float*  b1s  = (float*)(ws + 512 * 1024 + 30720);   // 768 B
    float*  w2s  = (float*)(ws + 512 * 1024 + 31488);   // 768 B

    epn_frag_kernel<<<11, 256, 0, stream>>>(W0, W1, b1, W2, q, fw0e, fw1, b1s, w2s, qout);
    for (int t = 0; t < 3; ++t) {
        epn_proj_kernel<<<256, 256, 0, stream>>>(h, qout, W0 + t * 80 * 64, b0 + t * 64,
                                                 Pws, Qws);
        epn_main_kernel<<<dim3(16, 64), 256, 0, stream>>>(
            e, mask, Pws, Qws,
            fw0e + (size_t)t * 4 * 64, fw1 + (size_t)t * 8 * 64,
            b1s + t * 64, w2s + t * 64, qout);
    }
}